// Round 1
// baseline (4253.186 us; speedup 1.0000x reference)
//
#include <hip/hip_runtime.h>

// GRU LM: L=2, B=64, S=64, E=H=1024, V=32000. All ref math fp32; we use bf16 MFMA.
#define NB_REC 128          // persistent recurrence grid (must be <= CU count for co-residency)
#define SBV    131072000    // S*B*V logits element count

typedef __bf16 bf16x8 __attribute__((ext_vector_type(8)));
typedef float  f32x4  __attribute__((ext_vector_type(4)));
typedef unsigned short u16;

__device__ __forceinline__ u16 f2bf(float f) {
  union { float f; unsigned u; } c; c.f = f;
  return (u16)((c.u + 0x7fffu + ((c.u >> 16) & 1u)) >> 16);  // RNE
}
__device__ __forceinline__ float sigm(float x) { return 1.f / (1.f + __expf(-x)); }
__device__ __forceinline__ float tanh_f(float x) { return 2.f / (1.f + __expf(-2.f * x)) - 1.f; }

// ---------------- prep kernels ----------------

// fp32 -> bf16, vectorized x4, grid-stride
__global__ void k_cvtv(const float* __restrict__ src, u16* __restrict__ dst, int n4) {
  const float4* s4 = (const float4*)src;
  ushort4* d4 = (ushort4*)dst;
  for (int i = blockIdx.x * blockDim.x + threadIdx.x; i < n4; i += gridDim.x * blockDim.x) {
    float4 v = s4[i];
    ushort4 o; o.x = f2bf(v.x); o.y = f2bf(v.y); o.z = f2bf(v.z); o.w = f2bf(v.w);
    d4[i] = o;
  }
}

// pack {X,Z,H} gate matrices of one layer into [3072][1024] bf16 (rows 0..1023 = X gate, etc.)
__global__ void k_pack3(const float* __restrict__ sx, const float* __restrict__ sz,
                        const float* __restrict__ sh, int srcOff, u16* __restrict__ dst) {
  int i = blockIdx.x * blockDim.x + threadIdx.x;  // over 3M/4 float4s
  if (i >= 786432) return;
  int g = i >> 18;            // 0..2 gate
  int r4 = i & 262143;        // float4 index within 1M-elem matrix
  const float* s = (g == 0 ? sx : (g == 1 ? sz : sh)) + srcOff;
  float4 v = ((const float4*)s)[r4];
  ushort4 o; o.x = f2bf(v.x); o.y = f2bf(v.y); o.z = f2bf(v.z); o.w = f2bf(v.w);
  ((ushort4*)dst)[i] = o;
}

// embedding gather -> bf16 [4096][1024]
__global__ void k_embed(const int* __restrict__ idx, const float* __restrict__ emb,
                        u16* __restrict__ xe) {
  int i = blockIdx.x * blockDim.x + threadIdx.x;  // over 4096*256 float4s
  if (i >= 1048576) return;
  int row = i >> 8, k4 = i & 255;
  int e = idx[row];
  float4 v = ((const float4*)emb)[(size_t)e * 256 + k4];
  ushort4 o; o.x = f2bf(v.x); o.y = f2bf(v.y); o.z = f2bf(v.z); o.w = f2bf(v.w);
  ((ushort4*)xe)[i] = o;
}

// ---------------- GEMM: C[M,N] = A[M,K] @ B[N,K]^T (+bias), bf16 in / fp32 out ----------------
// m97-style: 128x128 tile, BK=32, 4 waves of 64x64, global_load_lds width-16 staging.
template<bool BIAS>
__global__ __launch_bounds__(256) void gemm_bt(const u16* __restrict__ A, const u16* __restrict__ Bm,
                                               float* __restrict__ C, const float* __restrict__ bias,
                                               int M, int N, int K, int mtiles) {
  __shared__ u16 As[128 * 32];
  __shared__ u16 Bs[128 * 32];
  const int tid = threadIdx.x;
  const int bm = blockIdx.x % mtiles, bn = blockIdx.x / mtiles;
  const int m0 = bm * 128, n0 = bn * 128;
  const int lane = tid & 63, w = tid >> 6, wm = w & 1, wn = w >> 1;
  const int la = lane & 15, lk = lane >> 4;
  const int srow = tid >> 2, sk = (tid & 3) * 8;  // staging: row, k-elem offset
  f32x4 acc[4][4] = {};
  for (int kt = 0; kt < K; kt += 32) {
    const u16* srcA0 = A + (size_t)(m0 + srow) * K + kt + sk;
    const u16* srcA1 = A + (size_t)(m0 + srow + 64) * K + kt + sk;
    const u16* srcB0 = Bm + (size_t)(n0 + srow) * K + kt + sk;
    const u16* srcB1 = Bm + (size_t)(n0 + srow + 64) * K + kt + sk;
    __builtin_amdgcn_global_load_lds((const __attribute__((address_space(1))) void*)srcA0,
        (__attribute__((address_space(3))) void*)((char*)As + tid * 16), 16, 0, 0);
    __builtin_amdgcn_global_load_lds((const __attribute__((address_space(1))) void*)srcA1,
        (__attribute__((address_space(3))) void*)((char*)As + 4096 + tid * 16), 16, 0, 0);
    __builtin_amdgcn_global_load_lds((const __attribute__((address_space(1))) void*)srcB0,
        (__attribute__((address_space(3))) void*)((char*)Bs + tid * 16), 16, 0, 0);
    __builtin_amdgcn_global_load_lds((const __attribute__((address_space(1))) void*)srcB1,
        (__attribute__((address_space(3))) void*)((char*)Bs + 4096 + tid * 16), 16, 0, 0);
    __syncthreads();
    bf16x8 av[4], bv[4];
    #pragma unroll
    for (int m = 0; m < 4; ++m)
      av[m] = *(const bf16x8*)(As + (wm * 64 + m * 16 + la) * 32 + lk * 8);
    #pragma unroll
    for (int n = 0; n < 4; ++n)
      bv[n] = *(const bf16x8*)(Bs + (wn * 64 + n * 16 + la) * 32 + lk * 8);
    #pragma unroll
    for (int m = 0; m < 4; ++m)
      #pragma unroll
      for (int n = 0; n < 4; ++n)
        acc[m][n] = __builtin_amdgcn_mfma_f32_16x16x32_bf16(av[m], bv[n], acc[m][n], 0, 0, 0);
    __syncthreads();
  }
  #pragma unroll
  for (int n = 0; n < 4; ++n) {
    const int gc = n0 + wn * 64 + n * 16 + la;
    const float bb = BIAS ? bias[gc] : 0.f;
    #pragma unroll
    for (int m = 0; m < 4; ++m) {
      const int gr0 = m0 + wm * 64 + m * 16 + lk * 4;
      #pragma unroll
      for (int r = 0; r < 4; ++r)
        C[(size_t)(gr0 + r) * N + gc] = acc[m][n][r] + bb;
    }
  }
}

// ---------------- persistent recurrence ----------------
// Custom device-scope barrier. 128 blocks (<=256 CUs -> co-resident). Spin-guarded.
__device__ __forceinline__ void gbar(unsigned* flags, unsigned* release, unsigned ph) {
  __syncthreads();
  __builtin_amdgcn_fence(__ATOMIC_RELEASE, "agent");  // flush dirty L2 (cross-XCD visibility)
  if (threadIdx.x == 0)
    __hip_atomic_store(&flags[blockIdx.x], ph, __ATOMIC_RELAXED, __HIP_MEMORY_SCOPE_AGENT);
  if (blockIdx.x == 0) {
    if ((int)threadIdx.x < NB_REC) {
      int g = 0;
      while (__hip_atomic_load(&flags[threadIdx.x], __ATOMIC_RELAXED, __HIP_MEMORY_SCOPE_AGENT) < ph) {
        __builtin_amdgcn_s_sleep(2);
        if (++g > 2000000) break;  // hang guard
      }
    }
    __syncthreads();
    if (threadIdx.x == 0)
      __hip_atomic_store(release, ph, __ATOMIC_RELAXED, __HIP_MEMORY_SCOPE_AGENT);
  } else {
    if (threadIdx.x == 0) {
      int g = 0;
      while (__hip_atomic_load(release, __ATOMIC_RELAXED, __HIP_MEMORY_SCOPE_AGENT) < ph) {
        __builtin_amdgcn_s_sleep(2);
        if (++g > 2000000) break;
      }
    }
    __syncthreads();
  }
  __builtin_amdgcn_fence(__ATOMIC_ACQUIRE, "agent");  // invalidate L1/L2 before reading fresh data
}

// Layer-pipelined GRU: iter i runs L0@t=i and L1@t=i-1. Two phases/iter:
//  A: r,z = sigmoid(x-proj + h@U{r,z}^T + b); store rh=bf16(r*h); keep z in regs.
//  B: hcand = tanh(x-proj + rh@Uh^T + bh); h = (1-z)h + z*hcand; store bf16 h.
// L1's x-projections are folded in as a second K=1024 MFMA pass (x = H0seq[t]).
// fp32 h state lives in registers (block owns a fixed [32 rows x 32 cols] slice).
__global__ __launch_bounds__(256) void k_recur(
    const u16* __restrict__ hinitb,    // [2][64][1024] bf16 of initial hidden
    const float* __restrict__ hidden,  // [2][64][1024] fp32
    const float* __restrict__ X0,      // [64][64][3072] layer-0 x-projections
    const u16* __restrict__ Ucat0, const u16* __restrict__ Ucat1,  // [3072][1024] {Ur|Uz|Uh}
    const u16* __restrict__ Wcat1,                                  // [3072][1024] {Wx|Wz|Wh} layer1
    const float* __restrict__ br, const float* __restrict__ bz, const float* __restrict__ bh,
    u16* __restrict__ H0seq, u16* __restrict__ H1seq,  // [64][64][1024] bf16 hidden per step
    u16* __restrict__ RH0, u16* __restrict__ RH1,      // [64][64][1024] bf16 r*h per step
    float* __restrict__ houtf,                          // d_out + SBV : [2][64][1024]
    unsigned* flags, unsigned* release) {
  const int tid = threadIdx.x, bid = blockIdx.x;
  const int layer = bid >> 6, r6 = bid & 63, bg = r6 >> 5, cc = r6 & 31;
  const int lane = tid & 63, w = tid >> 6, wm = w & 1, wn = w >> 1;
  const int la = lane & 15, lk = lane >> 4;
  const int b0 = bg * 32 + wm * 16;   // wave's first batch row
  const int j0 = cc * 32 + wn * 16;   // wave's first output col
  const int jl = j0 + la;             // this lane's output col (C/D: col = lane&15)
  const u16* Ucat = layer ? Ucat1 : Ucat0;
  u16* Hseq = layer ? H1seq : H0seq;
  u16* RHl = layer ? RH1 : RH0;
  const u16* hinit = hinitb + layer * 65536;

  float h_reg[4], z_reg[4];
  #pragma unroll
  for (int r = 0; r < 4; ++r)
    h_reg[r] = hidden[layer * 65536 + (b0 + lk * 4 + r) * 1024 + jl];
  const float bR = br[layer * 1024 + jl], bZ = bz[layer * 1024 + jl], bH = bh[layer * 1024 + jl];

  // fixed per-lane weight row bases (B-operand: col = lane&15, k-chunk = lane>>4)
  const u16* BrR = Ucat + ((size_t)(j0 + la)) * 1024 + lk * 8;
  const u16* BrZ = Ucat + ((size_t)(1024 + j0 + la)) * 1024 + lk * 8;
  const u16* BrH = Ucat + ((size_t)(2048 + j0 + la)) * 1024 + lk * 8;
  const u16* WrR = Wcat1 + ((size_t)(j0 + la)) * 1024 + lk * 8;
  const u16* WrZ = Wcat1 + ((size_t)(1024 + j0 + la)) * 1024 + lk * 8;
  const u16* WrH = Wcat1 + ((size_t)(2048 + j0 + la)) * 1024 + lk * 8;

  unsigned ph = 0;
  for (int i = 0; i <= 64; ++i) {
    const int t = layer ? (i - 1) : i;
    const bool act = layer ? (i >= 1) : (i < 64);
    // ---- phase A: r,z gates ----
    if (act) {
      const u16* Ah = (t == 0) ? hinit : (Hseq + (size_t)(t - 1) * 65536);
      const u16* ArA = Ah + (b0 + la) * 1024 + lk * 8;  // A: row = lane&15
      f32x4 accR = {0.f, 0.f, 0.f, 0.f}, accZ = {0.f, 0.f, 0.f, 0.f};
      if (layer == 0) {
        #pragma unroll 4
        for (int ks = 0; ks < 32; ++ks) {
          bf16x8 a = *(const bf16x8*)(ArA + ks * 32);
          accR = __builtin_amdgcn_mfma_f32_16x16x32_bf16(a, *(const bf16x8*)(BrR + ks * 32), accR, 0, 0, 0);
          accZ = __builtin_amdgcn_mfma_f32_16x16x32_bf16(a, *(const bf16x8*)(BrZ + ks * 32), accZ, 0, 0, 0);
        }
      } else {
        const u16* ArX = H0seq + (size_t)t * 65536 + (b0 + la) * 1024 + lk * 8;
        #pragma unroll 4
        for (int ks = 0; ks < 32; ++ks) {
          bf16x8 a = *(const bf16x8*)(ArA + ks * 32);
          bf16x8 x = *(const bf16x8*)(ArX + ks * 32);
          accR = __builtin_amdgcn_mfma_f32_16x16x32_bf16(a, *(const bf16x8*)(BrR + ks * 32), accR, 0, 0, 0);
          accZ = __builtin_amdgcn_mfma_f32_16x16x32_bf16(a, *(const bf16x8*)(BrZ + ks * 32), accZ, 0, 0, 0);
          accR = __builtin_amdgcn_mfma_f32_16x16x32_bf16(x, *(const bf16x8*)(WrR + ks * 32), accR, 0, 0, 0);
          accZ = __builtin_amdgcn_mfma_f32_16x16x32_bf16(x, *(const bf16x8*)(WrZ + ks * 32), accZ, 0, 0, 0);
        }
      }
      #pragma unroll
      for (int r = 0; r < 4; ++r) {
        const int row = b0 + lk * 4 + r;  // C/D: row = (lane>>4)*4 + reg
        float pr = accR[r] + bR, pz = accZ[r] + bZ;
        if (layer == 0) {
          const float* xp = X0 + ((size_t)(t * 64 + row)) * 3072 + jl;
          pr += xp[0]; pz += xp[1024];
        }
        float rv = sigm(pr);
        z_reg[r] = sigm(pz);
        RHl[(size_t)(t * 64 + row) * 1024 + jl] = f2bf(rv * h_reg[r]);
      }
    }
    gbar(flags, release, ++ph);
    // ---- phase B: candidate + state update ----
    if (act) {
      const u16* ArRH = RHl + (size_t)(t * 64 + b0 + la) * 1024 + lk * 8;
      f32x4 accH = {0.f, 0.f, 0.f, 0.f};
      if (layer == 0) {
        #pragma unroll 4
        for (int ks = 0; ks < 32; ++ks) {
          bf16x8 a = *(const bf16x8*)(ArRH + ks * 32);
          accH = __builtin_amdgcn_mfma_f32_16x16x32_bf16(a, *(const bf16x8*)(BrH + ks * 32), accH, 0, 0, 0);
        }
      } else {
        const u16* ArX = H0seq + (size_t)t * 65536 + (b0 + la) * 1024 + lk * 8;
        #pragma unroll 4
        for (int ks = 0; ks < 32; ++ks) {
          bf16x8 a = *(const bf16x8*)(ArRH + ks * 32);
          bf16x8 x = *(const bf16x8*)(ArX + ks * 32);
          accH = __builtin_amdgcn_mfma_f32_16x16x32_bf16(a, *(const bf16x8*)(BrH + ks * 32), accH, 0, 0, 0);
          accH = __builtin_amdgcn_mfma_f32_16x16x32_bf16(x, *(const bf16x8*)(WrH + ks * 32), accH, 0, 0, 0);
        }
      }
      #pragma unroll
      for (int r = 0; r < 4; ++r) {
        const int row = b0 + lk * 4 + r;
        float pre = accH[r] + bH;
        if (layer == 0) pre += X0[((size_t)(t * 64 + row)) * 3072 + 2048 + jl];
        float hc = tanh_f(pre);
        float hn = h_reg[r] + z_reg[r] * (hc - h_reg[r]);  // (1-z)h + z*hcand
        h_reg[r] = hn;
        Hseq[(size_t)(t * 64 + row) * 1024 + jl] = f2bf(hn);
        if (t == 63) houtf[layer * 65536 + row * 1024 + jl] = hn;
      }
    }
    gbar(flags, release, ++ph);
  }
}

// ---------------- host launch ----------------
extern "C" void kernel_launch(void* const* d_in, const int* in_sizes, int n_in,
                              void* d_out, int out_size, void* d_ws, size_t ws_size,
                              hipStream_t stream) {
  const int* inputs = (const int*)d_in[0];
  const float* hidden = (const float*)d_in[1];
  const float* emb = (const float*)d_in[2];
  const float* Wx = (const float*)d_in[3];
  const float* Ur = (const float*)d_in[4];
  const float* br = (const float*)d_in[5];
  const float* Wz = (const float*)d_in[6];
  const float* Uz = (const float*)d_in[7];
  const float* bz = (const float*)d_in[8];
  const float* Wh = (const float*)d_in[9];
  const float* Uh = (const float*)d_in[10];
  const float* bh = (const float*)d_in[11];
  const float* decW = (const float*)d_in[12];
  const float* decb = (const float*)d_in[13];
  float* out = (float*)d_out;

  char* ws = (char*)d_ws;
  size_t off = 0;
  auto alloc = [&](size_t bytes) { char* p = ws + off; off += (bytes + 255) & ~(size_t)255; return p; };
  unsigned* flags = (unsigned*)alloc(4096);          // flags[128] + release @ [256]
  unsigned* release = flags + 256;
  u16* hinitb = (u16*)alloc((size_t)2 * 64 * 1024 * 2);
  u16* xe     = (u16*)alloc((size_t)4096 * 1024 * 2);
  u16* Wcat0b = (u16*)alloc((size_t)3072 * 1024 * 2);
  u16* Wcat1b = (u16*)alloc((size_t)3072 * 1024 * 2);
  u16* Ucat0b = (u16*)alloc((size_t)3072 * 1024 * 2);
  u16* Ucat1b = (u16*)alloc((size_t)3072 * 1024 * 2);
  u16* decWb  = (u16*)alloc((size_t)32000 * 1024 * 2);
  float* X0   = (float*)alloc((size_t)4096 * 3072 * 4);
  u16* H0seq  = (u16*)alloc((size_t)4096 * 1024 * 2);
  u16* H1seq  = (u16*)alloc((size_t)4096 * 1024 * 2);
  u16* RH0    = (u16*)alloc((size_t)4096 * 1024 * 2);
  u16* RH1    = (u16*)alloc((size_t)4096 * 1024 * 2);

  hipMemsetAsync(flags, 0, 4096, stream);
  k_cvtv<<<128, 256, 0, stream>>>(hidden, hinitb, 32768);
  k_pack3<<<3072, 256, 0, stream>>>(Wx, Wz, Wh, 0, Wcat0b);
  k_pack3<<<3072, 256, 0, stream>>>(Wx, Wz, Wh, 1048576, Wcat1b);
  k_pack3<<<3072, 256, 0, stream>>>(Ur, Uz, Uh, 0, Ucat0b);
  k_pack3<<<3072, 256, 0, stream>>>(Ur, Uz, Uh, 1048576, Ucat1b);
  k_embed<<<4096, 256, 0, stream>>>(inputs, emb, xe);
  k_cvtv<<<4096, 256, 0, stream>>>(decW, decWb, 8192000);

  // layer-0 x-projections for all timesteps: [4096,1024] @ [3072,1024]^T
  gemm_bt<false><<<768, 256, 0, stream>>>(xe, Wcat0b, X0, nullptr, 4096, 3072, 1024, 32);

  // pipelined 2-layer recurrence (65 iters x 2 barriers)
  k_recur<<<NB_REC, 256, 0, stream>>>(hinitb, hidden, X0, Ucat0b, Ucat1b, Wcat1b,
                                      br, bz, bh, H0seq, H1seq, RH0, RH1,
                                      out + (size_t)SBV, flags, release);

  // decoder: logits[4096,32000] = H1seq @ decW^T + bias
  gemm_bt<true><<<8000, 256, 0, stream>>>(H1seq, decWb, out, decb, 4096, 32000, 1024, 32);
}

// Round 3
// 3175.692 us; speedup vs baseline: 1.3393x; 1.3393x over previous
//
#include <hip/hip_runtime.h>

// GRU LM: L=2, B=64, S=64, E=H=1024, V=32000. All ref math fp32; we use bf16 MFMA.
#define NB_REC 128          // persistent recurrence grid (<= 256 CUs -> co-resident)
#define SBV    131072000    // S*B*V logits element count

typedef __bf16 bf16x8 __attribute__((ext_vector_type(8)));
typedef float  f32x4  __attribute__((ext_vector_type(4)));
typedef unsigned short u16;

__device__ __forceinline__ u16 f2bf(float f) {
  union { float f; unsigned u; } c; c.f = f;
  return (u16)((c.u + 0x7fffu + ((c.u >> 16) & 1u)) >> 16);  // RNE
}
__device__ __forceinline__ float sigm(float x) { return 1.f / (1.f + __expf(-x)); }
__device__ __forceinline__ float tanh_f(float x) { return 2.f / (1.f + __expf(-2.f * x)) - 1.f; }

// ---------------- prep kernels ----------------

__global__ void k_cvtv(const float* __restrict__ src, u16* __restrict__ dst, int n4) {
  const float4* s4 = (const float4*)src;
  ushort4* d4 = (ushort4*)dst;
  for (int i = blockIdx.x * blockDim.x + threadIdx.x; i < n4; i += gridDim.x * blockDim.x) {
    float4 v = s4[i];
    ushort4 o; o.x = f2bf(v.x); o.y = f2bf(v.y); o.z = f2bf(v.z); o.w = f2bf(v.w);
    d4[i] = o;
  }
}

__global__ void k_pack3(const float* __restrict__ sx, const float* __restrict__ sz,
                        const float* __restrict__ sh, int srcOff, u16* __restrict__ dst) {
  int i = blockIdx.x * blockDim.x + threadIdx.x;  // over 3M/4 float4s
  if (i >= 786432) return;
  int g = i >> 18;            // 0..2 gate
  int r4 = i & 262143;        // float4 index within 1M-elem matrix
  const float* s = (g == 0 ? sx : (g == 1 ? sz : sh)) + srcOff;
  float4 v = ((const float4*)s)[r4];
  ushort4 o; o.x = f2bf(v.x); o.y = f2bf(v.y); o.z = f2bf(v.z); o.w = f2bf(v.w);
  ((ushort4*)dst)[i] = o;
}

__global__ void k_embed(const int* __restrict__ idx, const float* __restrict__ emb,
                        u16* __restrict__ xe) {
  int i = blockIdx.x * blockDim.x + threadIdx.x;  // over 4096*256 float4s
  if (i >= 1048576) return;
  int row = i >> 8, k4 = i & 255;
  int e = idx[row];
  float4 v = ((const float4*)emb)[(size_t)e * 256 + k4];
  ushort4 o; o.x = f2bf(v.x); o.y = f2bf(v.y); o.z = f2bf(v.z); o.w = f2bf(v.w);
  ((ushort4*)xe)[i] = o;
}

// ---------------- GEMM: C[M,N] = A[M,K] @ B[N,K]^T (+bias), bf16 in / fp32 out ----------------
template<bool BIAS>
__global__ __launch_bounds__(256) void gemm_bt(const u16* __restrict__ A, const u16* __restrict__ Bm,
                                               float* __restrict__ C, const float* __restrict__ bias,
                                               int M, int N, int K, int mtiles) {
  __shared__ u16 As[128 * 32];
  __shared__ u16 Bs[128 * 32];
  const int tid = threadIdx.x;
  const int bm = blockIdx.x % mtiles, bn = blockIdx.x / mtiles;
  const int m0 = bm * 128, n0 = bn * 128;
  const int lane = tid & 63, w = tid >> 6, wm = w & 1, wn = w >> 1;
  const int la = lane & 15, lk = lane >> 4;
  const int srow = tid >> 2, sk = (tid & 3) * 8;
  f32x4 acc[4][4] = {};
  for (int kt = 0; kt < K; kt += 32) {
    const u16* srcA0 = A + (size_t)(m0 + srow) * K + kt + sk;
    const u16* srcA1 = A + (size_t)(m0 + srow + 64) * K + kt + sk;
    const u16* srcB0 = Bm + (size_t)(n0 + srow) * K + kt + sk;
    const u16* srcB1 = Bm + (size_t)(n0 + srow + 64) * K + kt + sk;
    __builtin_amdgcn_global_load_lds((const __attribute__((address_space(1))) void*)srcA0,
        (__attribute__((address_space(3))) void*)((char*)As + tid * 16), 16, 0, 0);
    __builtin_amdgcn_global_load_lds((const __attribute__((address_space(1))) void*)srcA1,
        (__attribute__((address_space(3))) void*)((char*)As + 4096 + tid * 16), 16, 0, 0);
    __builtin_amdgcn_global_load_lds((const __attribute__((address_space(1))) void*)srcB0,
        (__attribute__((address_space(3))) void*)((char*)Bs + tid * 16), 16, 0, 0);
    __builtin_amdgcn_global_load_lds((const __attribute__((address_space(1))) void*)srcB1,
        (__attribute__((address_space(3))) void*)((char*)Bs + 4096 + tid * 16), 16, 0, 0);
    __syncthreads();
    bf16x8 av[4], bv[4];
    #pragma unroll
    for (int m = 0; m < 4; ++m)
      av[m] = *(const bf16x8*)(As + (wm * 64 + m * 16 + la) * 32 + lk * 8);
    #pragma unroll
    for (int n = 0; n < 4; ++n)
      bv[n] = *(const bf16x8*)(Bs + (wn * 64 + n * 16 + la) * 32 + lk * 8);
    #pragma unroll
    for (int m = 0; m < 4; ++m)
      #pragma unroll
      for (int n = 0; n < 4; ++n)
        acc[m][n] = __builtin_amdgcn_mfma_f32_16x16x32_bf16(av[m], bv[n], acc[m][n], 0, 0, 0);
    __syncthreads();
  }
  #pragma unroll
  for (int n = 0; n < 4; ++n) {
    const int gc = n0 + wn * 64 + n * 16 + la;
    const float bb = BIAS ? bias[gc] : 0.f;
    #pragma unroll
    for (int m = 0; m < 4; ++m) {
      const int gr0 = m0 + wm * 64 + m * 16 + lk * 4;
      #pragma unroll
      for (int r = 0; r < 4; ++r)
        C[(size_t)(gr0 + r) * N + gc] = acc[m][n][r] + bb;
    }
  }
}

// ---------------- persistent recurrence ----------------
// Coherence scheme: NO acquire fences (round-1 pathology: agent acquire invalidated
// L1/L2 every phase -> 637MB weight re-fetch, 3.7ms). Cross-block activations are
// written with sc1 (device-scope) stores and read with sc1 loads staged into LDS;
// weights use normal cached loads and stay L2-resident. Barrier = LLC atomic counter.

__device__ __forceinline__ void gbar2(unsigned* cnt, unsigned target) {
  __syncthreads();                                   // all LDS + reg work of this phase done
  asm volatile("s_waitcnt vmcnt(0)" ::: "memory");   // my sc1 stores are at coherence point
  if (threadIdx.x == 0) {
    __hip_atomic_fetch_add(cnt, 1u, __ATOMIC_RELEASE, __HIP_MEMORY_SCOPE_AGENT);
    unsigned g = 0;
    while (__hip_atomic_load(cnt, __ATOMIC_RELAXED, __HIP_MEMORY_SCOPE_AGENT) < target) {
      __builtin_amdgcn_s_sleep(2);
      if (++g > 20000000u) break;  // hang guard
    }
  }
  __syncthreads();
}

// Stage one K-half of a [32][1024] bf16 tile: [32 rows][512 cols] = 32KB into sA.
// Row stride in LDS = 1024B, XOR swizzle byte ^= (row&7)<<4 (G4: breaks the 1024B-stride
// bank conflict on the ds_read_b128 fragment reads). 2048 chunks of 16B / 256 threads.
__device__ __forceinline__ void stage1(const u16* __restrict__ gA, int half, char* sA, int tid) {
  uint4 ta[8];
  #pragma unroll
  for (int i = 0; i < 8; ++i) {
    int c = i * 256 + tid;                    // 0..2047
    int row = c >> 6, ce = (c & 63) * 8;      // 64 chunks/row, 8 u16 per chunk
    const u16* p = gA + row * 1024 + half * 512 + ce;
    asm volatile("global_load_dwordx4 %0, %1, off sc1" : "=v"(ta[i]) : "v"(p));
  }
  asm volatile("s_waitcnt vmcnt(0)" ::: "memory");
  #pragma unroll
  for (int i = 0; i < 8; ++i) {
    int c = i * 256 + tid;
    int row = c >> 6, cb = (c & 63) * 16;
    *(uint4*)(sA + ((row * 1024 + cb) ^ ((row & 7) << 4))) = ta[i];
  }
}

// Same, but two tiles (h + x) under a single vmcnt wait.
__device__ __forceinline__ void stage2(const u16* __restrict__ gA, const u16* __restrict__ gB,
                                       int half, char* sA, char* sB, int tid) {
  uint4 ta[8], tb[8];
  #pragma unroll
  for (int i = 0; i < 8; ++i) {
    int c = i * 256 + tid;
    int row = c >> 6, ce = (c & 63) * 8;
    const u16* pa = gA + row * 1024 + half * 512 + ce;
    const u16* pb = gB + row * 1024 + half * 512 + ce;
    asm volatile("global_load_dwordx4 %0, %1, off sc1" : "=v"(ta[i]) : "v"(pa));
    asm volatile("global_load_dwordx4 %0, %1, off sc1" : "=v"(tb[i]) : "v"(pb));
  }
  asm volatile("s_waitcnt vmcnt(0)" ::: "memory");
  #pragma unroll
  for (int i = 0; i < 8; ++i) {
    int c = i * 256 + tid;
    int row = c >> 6, cb = (c & 63) * 16;
    int off = (row * 1024 + cb) ^ ((row & 7) << 4);
    *(uint4*)(sA + off) = ta[i];
    *(uint4*)(sB + off) = tb[i];
  }
}

__device__ __forceinline__ bf16x8 ldsRd(const char* lds, int row, int ksl, int lk) {
  return *(const bf16x8*)(lds + ((row * 1024 + ksl * 64 + lk * 16) ^ ((row & 7) << 4)));
}

__global__ __launch_bounds__(256) void k_recur(
    const u16* __restrict__ hinitb,    // [2][64][1024] bf16 of initial hidden
    const float* __restrict__ hidden,  // [2][64][1024] fp32
    const float* __restrict__ X0,      // [64][64][3072] layer-0 x-projections
    const u16* __restrict__ Ucat0, const u16* __restrict__ Ucat1,  // [3072][1024] {Ur|Uz|Uh}
    const u16* __restrict__ Wcat1,                                  // [3072][1024] {Wx|Wz|Wh} layer1
    const float* __restrict__ br, const float* __restrict__ bz, const float* __restrict__ bh,
    u16* __restrict__ H0seq, u16* __restrict__ H1seq,  // [64][64][1024] bf16 hidden per step
    u16* __restrict__ RH0, u16* __restrict__ RH1,      // [64][64][1024] bf16 r*h per step
    float* __restrict__ houtf,                          // d_out + SBV : [2][64][1024]
    unsigned* cnt) {
  __shared__ char sMem[65536];        // sA: h / r*h half-tile (32KB); sB: layer-1 x half-tile
  char* sA = sMem;
  char* sB = sMem + 32768;
  const int tid = threadIdx.x, bid = blockIdx.x;
  const int layer = bid >> 6, r6 = bid & 63, bg = r6 >> 5, cc = r6 & 31;
  const int lane = tid & 63, w = tid >> 6, wm = w & 1, wn = w >> 1;
  const int la = lane & 15, lk = lane >> 4;
  const int rowbase = bg * 32;
  const int b0 = rowbase + wm * 16;   // wave's first batch row (global)
  const int rowA = wm * 16 + la;      // A-operand row, local to staged tile
  const int j0 = cc * 32 + wn * 16;   // wave's first output col
  const int jl = j0 + la;             // this lane's output col (C/D: col = lane&15)
  const u16* Ucat = layer ? Ucat1 : Ucat0;
  u16* Hseq = layer ? H1seq : H0seq;
  u16* RHl = layer ? RH1 : RH0;
  const u16* hinit = hinitb + layer * 65536;

  float h_reg[4], z_reg[4];
  #pragma unroll
  for (int r = 0; r < 4; ++r)
    h_reg[r] = hidden[layer * 65536 + (b0 + lk * 4 + r) * 1024 + jl];
  const float bR = br[layer * 1024 + jl], bZ = bz[layer * 1024 + jl], bH = bh[layer * 1024 + jl];

  // per-lane weight row bases (B-operand: col = lane&15, k-chunk = lane>>4); cached loads
  const u16* BrR = Ucat + ((size_t)(j0 + la)) * 1024 + lk * 8;
  const u16* BrZ = Ucat + ((size_t)(1024 + j0 + la)) * 1024 + lk * 8;
  const u16* BrH = Ucat + ((size_t)(2048 + j0 + la)) * 1024 + lk * 8;
  const u16* WrR = Wcat1 + ((size_t)(j0 + la)) * 1024 + lk * 8;
  const u16* WrZ = Wcat1 + ((size_t)(1024 + j0 + la)) * 1024 + lk * 8;
  const u16* WrH = Wcat1 + ((size_t)(2048 + j0 + la)) * 1024 + lk * 8;

  unsigned ph = 0;
  for (int i = 0; i <= 64; ++i) {
    const int t = layer ? (i - 1) : i;
    const bool act = layer ? (i >= 1) : (i < 64);
    // ---- phase A: r,z gates ----
    if (act) {
      const u16* hsrc = ((t == 0) ? hinit : (Hseq + (size_t)(t - 1) * 65536)) + rowbase * 1024;
      f32x4 accR = {0.f, 0.f, 0.f, 0.f}, accZ = {0.f, 0.f, 0.f, 0.f};
      for (int half = 0; half < 2; ++half) {
        if (layer == 0) {
          stage1(hsrc, half, sA, tid);
          __syncthreads();
          #pragma unroll 4
          for (int ksl = 0; ksl < 16; ++ksl) {
            const int ks = half * 16 + ksl;
            bf16x8 a = ldsRd(sA, rowA, ksl, lk);
            accR = __builtin_amdgcn_mfma_f32_16x16x32_bf16(a, *(const bf16x8*)(BrR + ks * 32), accR, 0, 0, 0);
            accZ = __builtin_amdgcn_mfma_f32_16x16x32_bf16(a, *(const bf16x8*)(BrZ + ks * 32), accZ, 0, 0, 0);
          }
        } else {
          stage2(hsrc, H0seq + (size_t)t * 65536 + rowbase * 1024, half, sA, sB, tid);
          __syncthreads();
          #pragma unroll 4
          for (int ksl = 0; ksl < 16; ++ksl) {
            const int ks = half * 16 + ksl;
            bf16x8 a = ldsRd(sA, rowA, ksl, lk);
            bf16x8 x = ldsRd(sB, rowA, ksl, lk);
            accR = __builtin_amdgcn_mfma_f32_16x16x32_bf16(a, *(const bf16x8*)(BrR + ks * 32), accR, 0, 0, 0);
            accZ = __builtin_amdgcn_mfma_f32_16x16x32_bf16(a, *(const bf16x8*)(BrZ + ks * 32), accZ, 0, 0, 0);
            accR = __builtin_amdgcn_mfma_f32_16x16x32_bf16(x, *(const bf16x8*)(WrR + ks * 32), accR, 0, 0, 0);
            accZ = __builtin_amdgcn_mfma_f32_16x16x32_bf16(x, *(const bf16x8*)(WrZ + ks * 32), accZ, 0, 0, 0);
          }
        }
        __syncthreads();
      }
      #pragma unroll
      for (int r = 0; r < 4; ++r) {
        const int row = b0 + lk * 4 + r;  // C/D: row = (lane>>4)*4 + reg
        float pr = accR[r] + bR, pz = accZ[r] + bZ;
        if (layer == 0) {
          const float* xp = X0 + ((size_t)(t * 64 + row)) * 3072 + jl;
          pr += xp[0]; pz += xp[1024];
        }
        float rv = sigm(pr);
        z_reg[r] = sigm(pz);
        unsigned v = f2bf(rv * h_reg[r]);
        u16* p = RHl + (size_t)(t * 64 + row) * 1024 + jl;
        asm volatile("global_store_short %0, %1, off sc1" :: "v"(p), "v"(v));
      }
    }
    gbar2(cnt, NB_REC * (++ph));
    // ---- phase B: candidate + state update ----
    if (act) {
      const u16* rhsrc = RHl + (size_t)t * 65536 + rowbase * 1024;
      f32x4 accH = {0.f, 0.f, 0.f, 0.f};
      for (int half = 0; half < 2; ++half) {
        if (layer == 0) {
          stage1(rhsrc, half, sA, tid);
          __syncthreads();
          #pragma unroll 4
          for (int ksl = 0; ksl < 16; ++ksl) {
            const int ks = half * 16 + ksl;
            bf16x8 a = ldsRd(sA, rowA, ksl, lk);
            accH = __builtin_amdgcn_mfma_f32_16x16x32_bf16(a, *(const bf16x8*)(BrH + ks * 32), accH, 0, 0, 0);
          }
        } else {
          stage2(rhsrc, H0seq + (size_t)t * 65536 + rowbase * 1024, half, sA, sB, tid);
          __syncthreads();
          #pragma unroll 4
          for (int ksl = 0; ksl < 16; ++ksl) {
            const int ks = half * 16 + ksl;
            bf16x8 a = ldsRd(sA, rowA, ksl, lk);
            bf16x8 x = ldsRd(sB, rowA, ksl, lk);
            accH = __builtin_amdgcn_mfma_f32_16x16x32_bf16(a, *(const bf16x8*)(BrH + ks * 32), accH, 0, 0, 0);
            accH = __builtin_amdgcn_mfma_f32_16x16x32_bf16(x, *(const bf16x8*)(WrH + ks * 32), accH, 0, 0, 0);
          }
        }
        __syncthreads();
      }
      #pragma unroll
      for (int r = 0; r < 4; ++r) {
        const int row = b0 + lk * 4 + r;
        float pre = accH[r] + bH;
        if (layer == 0) pre += X0[((size_t)(t * 64 + row)) * 3072 + 2048 + jl];
        float hc = tanh_f(pre);
        float hn = h_reg[r] + z_reg[r] * (hc - h_reg[r]);  // (1-z)h + z*hcand
        h_reg[r] = hn;
        unsigned v = f2bf(hn);
        u16* p = Hseq + (size_t)(t * 64 + row) * 1024 + jl;
        asm volatile("global_store_short %0, %1, off sc1" :: "v"(p), "v"(v));
        if (t == 63) houtf[layer * 65536 + row * 1024 + jl] = hn;
      }
    }
    gbar2(cnt, NB_REC * (++ph));
  }
}

// ---------------- host launch ----------------
extern "C" void kernel_launch(void* const* d_in, const int* in_sizes, int n_in,
                              void* d_out, int out_size, void* d_ws, size_t ws_size,
                              hipStream_t stream) {
  const int* inputs = (const int*)d_in[0];
  const float* hidden = (const float*)d_in[1];
  const float* emb = (const float*)d_in[2];
  const float* Wx = (const float*)d_in[3];
  const float* Ur = (const float*)d_in[4];
  const float* br = (const float*)d_in[5];
  const float* Wz = (const float*)d_in[6];
  const float* Uz = (const float*)d_in[7];
  const float* bz = (const float*)d_in[8];
  const float* Wh = (const float*)d_in[9];
  const float* Uh = (const float*)d_in[10];
  const float* bh = (const float*)d_in[11];
  const float* decW = (const float*)d_in[12];
  const float* decb = (const float*)d_in[13];
  float* out = (float*)d_out;

  char* ws = (char*)d_ws;
  size_t off = 0;
  auto alloc = [&](size_t bytes) { char* p = ws + off; off += (bytes + 255) & ~(size_t)255; return p; };
  unsigned* cnt = (unsigned*)alloc(4096);
  u16* hinitb = (u16*)alloc((size_t)2 * 64 * 1024 * 2);
  u16* xe     = (u16*)alloc((size_t)4096 * 1024 * 2);
  u16* Wcat0b = (u16*)alloc((size_t)3072 * 1024 * 2);
  u16* Wcat1b = (u16*)alloc((size_t)3072 * 1024 * 2);
  u16* Ucat0b = (u16*)alloc((size_t)3072 * 1024 * 2);
  u16* Ucat1b = (u16*)alloc((size_t)3072 * 1024 * 2);
  u16* decWb  = (u16*)alloc((size_t)32000 * 1024 * 2);
  float* X0   = (float*)alloc((size_t)4096 * 3072 * 4);
  u16* H0seq  = (u16*)alloc((size_t)4096 * 1024 * 2);
  u16* H1seq  = (u16*)alloc((size_t)4096 * 1024 * 2);
  u16* RH0    = (u16*)alloc((size_t)4096 * 1024 * 2);
  u16* RH1    = (u16*)alloc((size_t)4096 * 1024 * 2);

  hipMemsetAsync(cnt, 0, 4096, stream);
  k_cvtv<<<128, 256, 0, stream>>>(hidden, hinitb, 32768);
  k_pack3<<<3072, 256, 0, stream>>>(Wx, Wz, Wh, 0, Wcat0b);
  k_pack3<<<3072, 256, 0, stream>>>(Wx, Wz, Wh, 1048576, Wcat1b);
  k_pack3<<<3072, 256, 0, stream>>>(Ur, Uz, Uh, 0, Ucat0b);
  k_pack3<<<3072, 256, 0, stream>>>(Ur, Uz, Uh, 1048576, Ucat1b);
  k_embed<<<4096, 256, 0, stream>>>(inputs, emb, xe);
  k_cvtv<<<4096, 256, 0, stream>>>(decW, decWb, 8192000);

  // layer-0 x-projections for all timesteps: [4096,1024] @ [3072,1024]^T
  gemm_bt<false><<<768, 256, 0, stream>>>(xe, Wcat0b, X0, nullptr, 4096, 3072, 1024, 32);

  // pipelined 2-layer recurrence (65 iters x 2 barriers)
  k_recur<<<NB_REC, 256, 0, stream>>>(hinitb, hidden, X0, Ucat0b, Ucat1b, Wcat1b,
                                      br, bz, bh, H0seq, H1seq, RH0, RH1,
                                      out + (size_t)SBV, cnt);

  // decoder: logits[4096,32000] = H1seq @ decW^T + bias
  gemm_bt<true><<<8000, 256, 0, stream>>>(H1seq, decWb, out, decb, 4096, 32000, 1024, 32);
}

// Round 4
// 2580.810 us; speedup vs baseline: 1.6480x; 1.2305x over previous
//
#include <hip/hip_runtime.h>

// GRU LM: L=2, B=64, S=64, E=H=1024, V=32000. All ref math fp32; we use bf16 MFMA.
#define NB_REC 128          // persistent recurrence grid (<= 256 CUs -> co-resident)
#define SBV    131072000    // S*B*V logits element count

typedef __bf16 bf16x8 __attribute__((ext_vector_type(8)));
typedef float  f32x4  __attribute__((ext_vector_type(4)));
typedef unsigned short u16;

__device__ __forceinline__ u16 f2bf(float f) {
  union { float f; unsigned u; } c; c.f = f;
  return (u16)((c.u + 0x7fffu + ((c.u >> 16) & 1u)) >> 16);  // RNE
}
__device__ __forceinline__ float sigm(float x) { return 1.f / (1.f + __expf(-x)); }
__device__ __forceinline__ float tanh_f(float x) { return 2.f / (1.f + __expf(-2.f * x)) - 1.f; }

// ---------------- prep kernels ----------------

__global__ void k_cvtv(const float* __restrict__ src, u16* __restrict__ dst, int n4) {
  const float4* s4 = (const float4*)src;
  ushort4* d4 = (ushort4*)dst;
  for (int i = blockIdx.x * blockDim.x + threadIdx.x; i < n4; i += gridDim.x * blockDim.x) {
    float4 v = s4[i];
    ushort4 o; o.x = f2bf(v.x); o.y = f2bf(v.y); o.z = f2bf(v.z); o.w = f2bf(v.w);
    d4[i] = o;
  }
}

__global__ void k_pack3(const float* __restrict__ sx, const float* __restrict__ sz,
                        const float* __restrict__ sh, int srcOff, u16* __restrict__ dst) {
  int i = blockIdx.x * blockDim.x + threadIdx.x;  // over 3M/4 float4s
  if (i >= 786432) return;
  int g = i >> 18;            // 0..2 gate
  int r4 = i & 262143;        // float4 index within 1M-elem matrix
  const float* s = (g == 0 ? sx : (g == 1 ? sz : sh)) + srcOff;
  float4 v = ((const float4*)s)[r4];
  ushort4 o; o.x = f2bf(v.x); o.y = f2bf(v.y); o.z = f2bf(v.z); o.w = f2bf(v.w);
  ((ushort4*)dst)[i] = o;
}

__global__ void k_embed(const int* __restrict__ idx, const float* __restrict__ emb,
                        u16* __restrict__ xe) {
  int i = blockIdx.x * blockDim.x + threadIdx.x;  // over 4096*256 float4s
  if (i >= 1048576) return;
  int row = i >> 8, k4 = i & 255;
  int e = idx[row];
  float4 v = ((const float4*)emb)[(size_t)e * 256 + k4];
  ushort4 o; o.x = f2bf(v.x); o.y = f2bf(v.y); o.z = f2bf(v.z); o.w = f2bf(v.w);
  ((ushort4*)xe)[i] = o;
}

// ---------------- GEMM: C[M,N] = A[M,K] @ B[N,K]^T (+bias), bf16 in / fp32 out ----------------
template<bool BIAS>
__global__ __launch_bounds__(256) void gemm_bt(const u16* __restrict__ A, const u16* __restrict__ Bm,
                                               float* __restrict__ C, const float* __restrict__ bias,
                                               int M, int N, int K, int mtiles) {
  __shared__ u16 As[128 * 32];
  __shared__ u16 Bs[128 * 32];
  const int tid = threadIdx.x;
  const int bm = blockIdx.x % mtiles, bn = blockIdx.x / mtiles;
  const int m0 = bm * 128, n0 = bn * 128;
  const int lane = tid & 63, w = tid >> 6, wm = w & 1, wn = w >> 1;
  const int la = lane & 15, lk = lane >> 4;
  const int srow = tid >> 2, sk = (tid & 3) * 8;
  f32x4 acc[4][4] = {};
  for (int kt = 0; kt < K; kt += 32) {
    const u16* srcA0 = A + (size_t)(m0 + srow) * K + kt + sk;
    const u16* srcA1 = A + (size_t)(m0 + srow + 64) * K + kt + sk;
    const u16* srcB0 = Bm + (size_t)(n0 + srow) * K + kt + sk;
    const u16* srcB1 = Bm + (size_t)(n0 + srow + 64) * K + kt + sk;
    __builtin_amdgcn_global_load_lds((const __attribute__((address_space(1))) void*)srcA0,
        (__attribute__((address_space(3))) void*)((char*)As + tid * 16), 16, 0, 0);
    __builtin_amdgcn_global_load_lds((const __attribute__((address_space(1))) void*)srcA1,
        (__attribute__((address_space(3))) void*)((char*)As + 4096 + tid * 16), 16, 0, 0);
    __builtin_amdgcn_global_load_lds((const __attribute__((address_space(1))) void*)srcB0,
        (__attribute__((address_space(3))) void*)((char*)Bs + tid * 16), 16, 0, 0);
    __builtin_amdgcn_global_load_lds((const __attribute__((address_space(1))) void*)srcB1,
        (__attribute__((address_space(3))) void*)((char*)Bs + 4096 + tid * 16), 16, 0, 0);
    __syncthreads();
    bf16x8 av[4], bv[4];
    #pragma unroll
    for (int m = 0; m < 4; ++m)
      av[m] = *(const bf16x8*)(As + (wm * 64 + m * 16 + la) * 32 + lk * 8);
    #pragma unroll
    for (int n = 0; n < 4; ++n)
      bv[n] = *(const bf16x8*)(Bs + (wn * 64 + n * 16 + la) * 32 + lk * 8);
    #pragma unroll
    for (int m = 0; m < 4; ++m)
      #pragma unroll
      for (int n = 0; n < 4; ++n)
        acc[m][n] = __builtin_amdgcn_mfma_f32_16x16x32_bf16(av[m], bv[n], acc[m][n], 0, 0, 0);
    __syncthreads();
  }
  #pragma unroll
  for (int n = 0; n < 4; ++n) {
    const int gc = n0 + wn * 64 + n * 16 + la;
    const float bb = BIAS ? bias[gc] : 0.f;
    #pragma unroll
    for (int m = 0; m < 4; ++m) {
      const int gr0 = m0 + wm * 64 + m * 16 + lk * 4;
      #pragma unroll
      for (int r = 0; r < 4; ++r)
        C[(size_t)(gr0 + r) * N + gc] = acc[m][n][r] + bb;
    }
  }
}

// ---------------- persistent recurrence ----------------
// Coherence: cross-block activations written with sc1 (device-scope) stores and read
// with sc1 loads staged into LDS; weights use normal cached loads (stay L2-resident).
// Barrier: flags-array (parallel relaxed stores, NO atomic RMW -> no serialization,
// no compiler-emitted wbl2/inv). Explicit vmcnt(0) orders data stores before flag.

__device__ __forceinline__ void gbarF(unsigned* flags, unsigned* release, unsigned ph,
                                      int tid, int bid) {
  __syncthreads();                                   // phase's LDS reads & stores issued
  asm volatile("s_waitcnt vmcnt(0)" ::: "memory");   // sc1 data stores at coherence point
  if (tid == 0)
    __hip_atomic_store(&flags[bid], ph, __ATOMIC_RELAXED, __HIP_MEMORY_SCOPE_AGENT);
  if (bid == 0) {
    if (tid < 32) {                                  // 32 lanes x uint4 = 128 flags
      const uint4* fp = ((const uint4*)flags) + tid;
      unsigned g = 0;
      while (true) {
        uint4 v;
        asm volatile("global_load_dwordx4 %0, %1, off sc1\ns_waitcnt vmcnt(0)"
                     : "=v"(v) : "v"(fp) : "memory");
        if (v.x >= ph && v.y >= ph && v.z >= ph && v.w >= ph) break;
        __builtin_amdgcn_s_sleep(1);
        if (++g > 50000000u) break;                  // hang guard
      }
    }
    __syncthreads();
    if (tid == 0)
      __hip_atomic_store(release, ph, __ATOMIC_RELAXED, __HIP_MEMORY_SCOPE_AGENT);
  } else {
    if (tid == 0) {
      unsigned g = 0;
      while (__hip_atomic_load(release, __ATOMIC_RELAXED, __HIP_MEMORY_SCOPE_AGENT) < ph) {
        __builtin_amdgcn_s_sleep(1);
        if (++g > 50000000u) break;
      }
    }
    __syncthreads();
  }
}

// ---- full-tile staging (BIG): [32][1024] bf16 = 64KB, 4096 16B-chunks, 16/thread ----
// LDS row stride 2048B, XOR swizzle byte ^= (row&7)<<4 (G4: kills the power-of-2-stride
// bank conflict on ds_read_b128 fragment reads; 8-15 vs 0-7 alias 2-way = free).
__device__ __forceinline__ void stageF1(const u16* __restrict__ g, char* s, int tid) {
  uint4 t[16];
  #pragma unroll
  for (int i = 0; i < 16; ++i) {
    int c = i * 256 + tid;                    // 0..4095
    const u16* p = g + (c >> 7) * 1024 + (c & 127) * 8;
    asm volatile("global_load_dwordx4 %0, %1, off sc1" : "=v"(t[i]) : "v"(p));
  }
  asm volatile("s_waitcnt vmcnt(0)" ::: "memory");
  #pragma unroll
  for (int i = 0; i < 16; ++i) {
    int c = i * 256 + tid;
    int row = c >> 7, cb = (c & 127) * 16;
    *(uint4*)(s + ((row * 2048 + cb) ^ ((row & 7) << 4))) = t[i];
  }
}
__device__ __forceinline__ bf16x8 ldsF(const char* s, int row, int ks, int lk) {
  return *(const bf16x8*)(s + ((row * 2048 + ks * 64 + lk * 16) ^ ((row & 7) << 4)));
}

// ---- half-tile staging (fallback, 64KB LDS): [32][512] = 32KB, 8 chunks/thread ----
__device__ __forceinline__ void stageH1(const u16* __restrict__ g, int half, char* s, int tid) {
  uint4 t[8];
  #pragma unroll
  for (int i = 0; i < 8; ++i) {
    int c = i * 256 + tid;                    // 0..2047
    const u16* p = g + (c >> 6) * 1024 + half * 512 + (c & 63) * 8;
    asm volatile("global_load_dwordx4 %0, %1, off sc1" : "=v"(t[i]) : "v"(p));
  }
  asm volatile("s_waitcnt vmcnt(0)" ::: "memory");
  #pragma unroll
  for (int i = 0; i < 8; ++i) {
    int c = i * 256 + tid;
    int row = c >> 6, cb = (c & 63) * 16;
    *(uint4*)(s + ((row * 1024 + cb) ^ ((row & 7) << 4))) = t[i];
  }
}
__device__ __forceinline__ void stageH2(const u16* __restrict__ gA, const u16* __restrict__ gB,
                                        int half, char* sA, char* sB, int tid) {
  uint4 ta[8], tb[8];
  #pragma unroll
  for (int i = 0; i < 8; ++i) {
    int c = i * 256 + tid;
    int row = c >> 6, ce = (c & 63) * 8;
    const u16* pa = gA + row * 1024 + half * 512 + ce;
    const u16* pb = gB + row * 1024 + half * 512 + ce;
    asm volatile("global_load_dwordx4 %0, %1, off sc1" : "=v"(ta[i]) : "v"(pa));
    asm volatile("global_load_dwordx4 %0, %1, off sc1" : "=v"(tb[i]) : "v"(pb));
  }
  asm volatile("s_waitcnt vmcnt(0)" ::: "memory");
  #pragma unroll
  for (int i = 0; i < 8; ++i) {
    int c = i * 256 + tid;
    int row = c >> 6, cb = (c & 63) * 16;
    int off = (row * 1024 + cb) ^ ((row & 7) << 4);
    *(uint4*)(sA + off) = ta[i];
    *(uint4*)(sB + off) = tb[i];
  }
}
__device__ __forceinline__ bf16x8 ldsH(const char* s, int row, int ksl, int lk) {
  return *(const bf16x8*)(s + ((row * 1024 + ksl * 64 + lk * 16) ^ ((row & 7) << 4)));
}

// BIG=true : 128KB dynamic LDS (sA=64KB h/rh tile, sX=64KB x tile staged once/iter).
// BIG=false: 64KB dynamic LDS (r3 half-tile scheme, x restaged per half).
template<bool BIG>
__global__ __launch_bounds__(256) void k_recur(
    const u16* __restrict__ hinitb,    // [2][64][1024] bf16 of initial hidden
    const float* __restrict__ hidden,  // [2][64][1024] fp32
    const float* __restrict__ X0,      // [64][64][3072] layer-0 x-projections
    const u16* __restrict__ Ucat0, const u16* __restrict__ Ucat1,  // [3072][1024] {Ur|Uz|Uh}
    const u16* __restrict__ Wcat1,                                  // [3072][1024] {Wx|Wz|Wh} layer1
    const float* __restrict__ br, const float* __restrict__ bz, const float* __restrict__ bh,
    u16* __restrict__ H0seq, u16* __restrict__ H1seq,  // [64][64][1024] bf16 hidden per step
    u16* __restrict__ RH0, u16* __restrict__ RH1,      // [64][64][1024] bf16 r*h per step
    float* __restrict__ houtf,                          // d_out + SBV : [2][64][1024]
    unsigned* flags, unsigned* release) {
  extern __shared__ char sMem[];
  char* sA = sMem;
  char* sX = sMem + (BIG ? 65536 : 32768);
  const int tid = threadIdx.x, bid = blockIdx.x;
  const int layer = bid >> 6, r6 = bid & 63, bg = r6 >> 5, cc = r6 & 31;
  const int lane = tid & 63, w = tid >> 6, wm = w & 1, wn = w >> 1;
  const int la = lane & 15, lk = lane >> 4;
  const int rowbase = bg * 32;
  const int b0 = rowbase + wm * 16;   // wave's first batch row (global)
  const int rowA = wm * 16 + la;      // A-operand row, local to staged tile
  const int j0 = cc * 32 + wn * 16;   // wave's first output col
  const int jl = j0 + la;             // this lane's output col (C/D: col = lane&15)
  const u16* Ucat = layer ? Ucat1 : Ucat0;
  u16* Hseq = layer ? H1seq : H0seq;
  u16* RHl = layer ? RH1 : RH0;
  const u16* hinit = hinitb + layer * 65536;

  float h_reg[4], z_reg[4];
  #pragma unroll
  for (int r = 0; r < 4; ++r)
    h_reg[r] = hidden[layer * 65536 + (b0 + lk * 4 + r) * 1024 + jl];
  const float bR = br[layer * 1024 + jl], bZ = bz[layer * 1024 + jl], bH = bh[layer * 1024 + jl];

  // per-lane weight row bases (B-operand: col = lane&15, k-chunk = lane>>4); cached loads
  const u16* BrR = Ucat + ((size_t)(j0 + la)) * 1024 + lk * 8;
  const u16* BrZ = Ucat + ((size_t)(1024 + j0 + la)) * 1024 + lk * 8;
  const u16* BrH = Ucat + ((size_t)(2048 + j0 + la)) * 1024 + lk * 8;
  const u16* WrR = Wcat1 + ((size_t)(j0 + la)) * 1024 + lk * 8;
  const u16* WrZ = Wcat1 + ((size_t)(1024 + j0 + la)) * 1024 + lk * 8;
  const u16* WrH = Wcat1 + ((size_t)(2048 + j0 + la)) * 1024 + lk * 8;

  unsigned ph = 0;
  for (int i = 0; i <= 64; ++i) {
    const int t = layer ? (i - 1) : i;
    const bool act = layer ? (i >= 1) : (i < 64);
    // ---- phase A: r,z gates ----
    if (act) {
      const u16* hsrc = ((t == 0) ? hinit : (Hseq + (size_t)(t - 1) * 65536)) + rowbase * 1024;
      const u16* xsrc = H0seq + (size_t)t * 65536 + rowbase * 1024;
      f32x4 accR = {0.f, 0.f, 0.f, 0.f}, accZ = {0.f, 0.f, 0.f, 0.f};
      if (BIG) {
        stageF1(hsrc, sA, tid);
        if (layer) stageF1(xsrc, sX, tid);   // x staged ONCE per iteration, reused in phase B
        __syncthreads();
        if (layer == 0) {
          #pragma unroll 8
          for (int ks = 0; ks < 32; ++ks) {
            bf16x8 a = ldsF(sA, rowA, ks, lk);
            accR = __builtin_amdgcn_mfma_f32_16x16x32_bf16(a, *(const bf16x8*)(BrR + ks * 32), accR, 0, 0, 0);
            accZ = __builtin_amdgcn_mfma_f32_16x16x32_bf16(a, *(const bf16x8*)(BrZ + ks * 32), accZ, 0, 0, 0);
          }
        } else {
          #pragma unroll 4
          for (int ks = 0; ks < 32; ++ks) {
            bf16x8 a = ldsF(sA, rowA, ks, lk);
            bf16x8 x = ldsF(sX, rowA, ks, lk);
            accR = __builtin_amdgcn_mfma_f32_16x16x32_bf16(a, *(const bf16x8*)(BrR + ks * 32), accR, 0, 0, 0);
            accZ = __builtin_amdgcn_mfma_f32_16x16x32_bf16(a, *(const bf16x8*)(BrZ + ks * 32), accZ, 0, 0, 0);
            accR = __builtin_amdgcn_mfma_f32_16x16x32_bf16(x, *(const bf16x8*)(WrR + ks * 32), accR, 0, 0, 0);
            accZ = __builtin_amdgcn_mfma_f32_16x16x32_bf16(x, *(const bf16x8*)(WrZ + ks * 32), accZ, 0, 0, 0);
          }
        }
      } else {
        for (int half = 0; half < 2; ++half) {
          if (layer == 0) {
            stageH1(hsrc, half, sA, tid);
            __syncthreads();
            #pragma unroll 4
            for (int ksl = 0; ksl < 16; ++ksl) {
              const int ks = half * 16 + ksl;
              bf16x8 a = ldsH(sA, rowA, ksl, lk);
              accR = __builtin_amdgcn_mfma_f32_16x16x32_bf16(a, *(const bf16x8*)(BrR + ks * 32), accR, 0, 0, 0);
              accZ = __builtin_amdgcn_mfma_f32_16x16x32_bf16(a, *(const bf16x8*)(BrZ + ks * 32), accZ, 0, 0, 0);
            }
          } else {
            stageH2(hsrc, xsrc, half, sA, sX, tid);
            __syncthreads();
            #pragma unroll 4
            for (int ksl = 0; ksl < 16; ++ksl) {
              const int ks = half * 16 + ksl;
              bf16x8 a = ldsH(sA, rowA, ksl, lk);
              bf16x8 x = ldsH(sX, rowA, ksl, lk);
              accR = __builtin_amdgcn_mfma_f32_16x16x32_bf16(a, *(const bf16x8*)(BrR + ks * 32), accR, 0, 0, 0);
              accZ = __builtin_amdgcn_mfma_f32_16x16x32_bf16(a, *(const bf16x8*)(BrZ + ks * 32), accZ, 0, 0, 0);
              accR = __builtin_amdgcn_mfma_f32_16x16x32_bf16(x, *(const bf16x8*)(WrR + ks * 32), accR, 0, 0, 0);
              accZ = __builtin_amdgcn_mfma_f32_16x16x32_bf16(x, *(const bf16x8*)(WrZ + ks * 32), accZ, 0, 0, 0);
            }
          }
          __syncthreads();
        }
      }
      #pragma unroll
      for (int r = 0; r < 4; ++r) {
        const int row = b0 + lk * 4 + r;  // C/D: row = (lane>>4)*4 + reg
        float pr = accR[r] + bR, pz = accZ[r] + bZ;
        if (layer == 0) {
          const float* xp = X0 + ((size_t)(t * 64 + row)) * 3072 + jl;
          pr += xp[0]; pz += xp[1024];
        }
        float rv = sigm(pr);
        z_reg[r] = sigm(pz);
        unsigned v = f2bf(rv * h_reg[r]);
        u16* p = RHl + (size_t)(t * 64 + row) * 1024 + jl;
        asm volatile("global_store_short %0, %1, off sc1" :: "v"(p), "v"(v));
      }
    }
    gbarF(flags, release, ++ph, tid, bid);
    // ---- phase B: candidate + state update ----
    if (act) {
      const u16* rhsrc = RHl + (size_t)t * 65536 + rowbase * 1024;
      const u16* xsrc = H0seq + (size_t)t * 65536 + rowbase * 1024;
      f32x4 accH = {0.f, 0.f, 0.f, 0.f};
      if (BIG) {
        stageF1(rhsrc, sA, tid);          // sX still holds x from phase A
        __syncthreads();
        if (layer == 0) {
          #pragma unroll 8
          for (int ks = 0; ks < 32; ++ks) {
            bf16x8 a = ldsF(sA, rowA, ks, lk);
            accH = __builtin_amdgcn_mfma_f32_16x16x32_bf16(a, *(const bf16x8*)(BrH + ks * 32), accH, 0, 0, 0);
          }
        } else {
          #pragma unroll 8
          for (int ks = 0; ks < 32; ++ks) {
            bf16x8 a = ldsF(sA, rowA, ks, lk);
            bf16x8 x = ldsF(sX, rowA, ks, lk);
            accH = __builtin_amdgcn_mfma_f32_16x16x32_bf16(a, *(const bf16x8*)(BrH + ks * 32), accH, 0, 0, 0);
            accH = __builtin_amdgcn_mfma_f32_16x16x32_bf16(x, *(const bf16x8*)(WrH + ks * 32), accH, 0, 0, 0);
          }
        }
      } else {
        for (int half = 0; half < 2; ++half) {
          if (layer == 0) {
            stageH1(rhsrc, half, sA, tid);
            __syncthreads();
            #pragma unroll 4
            for (int ksl = 0; ksl < 16; ++ksl) {
              const int ks = half * 16 + ksl;
              bf16x8 a = ldsH(sA, rowA, ksl, lk);
              accH = __builtin_amdgcn_mfma_f32_16x16x32_bf16(a, *(const bf16x8*)(BrH + ks * 32), accH, 0, 0, 0);
            }
          } else {
            stageH2(rhsrc, xsrc, half, sA, sX, tid);
            __syncthreads();
            #pragma unroll 4
            for (int ksl = 0; ksl < 16; ++ksl) {
              const int ks = half * 16 + ksl;
              bf16x8 a = ldsH(sA, rowA, ksl, lk);
              bf16x8 x = ldsH(sX, rowA, ksl, lk);
              accH = __builtin_amdgcn_mfma_f32_16x16x32_bf16(a, *(const bf16x8*)(BrH + ks * 32), accH, 0, 0, 0);
              accH = __builtin_amdgcn_mfma_f32_16x16x32_bf16(x, *(const bf16x8*)(WrH + ks * 32), accH, 0, 0, 0);
            }
          }
          __syncthreads();
        }
      }
      #pragma unroll
      for (int r = 0; r < 4; ++r) {
        const int row = b0 + lk * 4 + r;
        float pre = accH[r] + bH;
        if (layer == 0) pre += X0[((size_t)(t * 64 + row)) * 3072 + 2048 + jl];
        float hc = tanh_f(pre);
        float hn = h_reg[r] + z_reg[r] * (hc - h_reg[r]);  // (1-z)h + z*hcand
        h_reg[r] = hn;
        unsigned v = f2bf(hn);
        u16* p = Hseq + (size_t)(t * 64 + row) * 1024 + jl;
        asm volatile("global_store_short %0, %1, off sc1" :: "v"(p), "v"(v));
        if (t == 63) houtf[layer * 65536 + row * 1024 + jl] = hn;
      }
    }
    gbarF(flags, release, ++ph, tid, bid);
  }
}

// ---------------- host launch ----------------
extern "C" void kernel_launch(void* const* d_in, const int* in_sizes, int n_in,
                              void* d_out, int out_size, void* d_ws, size_t ws_size,
                              hipStream_t stream) {
  const int* inputs = (const int*)d_in[0];
  const float* hidden = (const float*)d_in[1];
  const float* emb = (const float*)d_in[2];
  const float* Wx = (const float*)d_in[3];
  const float* Ur = (const float*)d_in[4];
  const float* br = (const float*)d_in[5];
  const float* Wz = (const float*)d_in[6];
  const float* Uz = (const float*)d_in[7];
  const float* bz = (const float*)d_in[8];
  const float* Wh = (const float*)d_in[9];
  const float* Uh = (const float*)d_in[10];
  const float* bh = (const float*)d_in[11];
  const float* decW = (const float*)d_in[12];
  const float* decb = (const float*)d_in[13];
  float* out = (float*)d_out;

  char* ws = (char*)d_ws;
  size_t off = 0;
  auto alloc = [&](size_t bytes) { char* p = ws + off; off += (bytes + 255) & ~(size_t)255; return p; };
  unsigned* flags = (unsigned*)alloc(4096);   // flags[128]; release at +256
  unsigned* release = flags + 256;
  u16* hinitb = (u16*)alloc((size_t)2 * 64 * 1024 * 2);
  u16* xe     = (u16*)alloc((size_t)4096 * 1024 * 2);
  u16* Wcat0b = (u16*)alloc((size_t)3072 * 1024 * 2);
  u16* Wcat1b = (u16*)alloc((size_t)3072 * 1024 * 2);
  u16* Ucat0b = (u16*)alloc((size_t)3072 * 1024 * 2);
  u16* Ucat1b = (u16*)alloc((size_t)3072 * 1024 * 2);
  u16* decWb  = (u16*)alloc((size_t)32000 * 1024 * 2);
  float* X0   = (float*)alloc((size_t)4096 * 3072 * 4);
  u16* H0seq  = (u16*)alloc((size_t)4096 * 1024 * 2);
  u16* H1seq  = (u16*)alloc((size_t)4096 * 1024 * 2);
  u16* RH0    = (u16*)alloc((size_t)4096 * 1024 * 2);
  u16* RH1    = (u16*)alloc((size_t)4096 * 1024 * 2);

  hipMemsetAsync(flags, 0, 4096, stream);
  k_cvtv<<<128, 256, 0, stream>>>(hidden, hinitb, 32768);
  k_pack3<<<3072, 256, 0, stream>>>(Wx, Wz, Wh, 0, Wcat0b);
  k_pack3<<<3072, 256, 0, stream>>>(Wx, Wz, Wh, 1048576, Wcat1b);
  k_pack3<<<3072, 256, 0, stream>>>(Ur, Uz, Uh, 0, Ucat0b);
  k_pack3<<<3072, 256, 0, stream>>>(Ur, Uz, Uh, 1048576, Ucat1b);
  k_embed<<<4096, 256, 0, stream>>>(inputs, emb, xe);
  k_cvtv<<<4096, 256, 0, stream>>>(decW, decWb, 8192000);

  // layer-0 x-projections for all timesteps: [4096,1024] @ [3072,1024]^T
  gemm_bt<false><<<768, 256, 0, stream>>>(xe, Wcat0b, X0, nullptr, 4096, 3072, 1024, 32);

  // pipelined 2-layer recurrence (65 iters x 2 barriers). Prefer 128KB-LDS variant;
  // deterministic fallback to 64KB half-tile variant if the attribute is refused.
  hipError_t eattr = hipFuncSetAttribute(reinterpret_cast<const void*>(&k_recur<true>),
                                         hipFuncAttributeMaxDynamicSharedMemorySize, 131072);
  if (eattr == hipSuccess) {
    k_recur<true><<<NB_REC, 256, 131072, stream>>>(hinitb, hidden, X0, Ucat0b, Ucat1b, Wcat1b,
                                                   br, bz, bh, H0seq, H1seq, RH0, RH1,
                                                   out + (size_t)SBV, flags, release);
  } else {
    (void)hipFuncSetAttribute(reinterpret_cast<const void*>(&k_recur<false>),
                              hipFuncAttributeMaxDynamicSharedMemorySize, 65536);
    k_recur<false><<<NB_REC, 256, 65536, stream>>>(hinitb, hidden, X0, Ucat0b, Ucat1b, Wcat1b,
                                                   br, bz, bh, H0seq, H1seq, RH0, RH1,
                                                   out + (size_t)SBV, flags, release);
  }

  // decoder: logits[4096,32000] = H1seq @ decW^T + bias
  gemm_bt<true><<<8000, 256, 0, stream>>>(H1seq, decWb, out, decb, 4096, 32000, 1024, 32);
}

// Round 6
// 2540.335 us; speedup vs baseline: 1.6743x; 1.0159x over previous
//
#include <hip/hip_runtime.h>

// GRU LM: L=2, B=64, S=64, E=H=1024, V=32000. All ref math fp32; we use bf16 MFMA.
#define NB_REC 128          // persistent recurrence grid (<= 256 CUs -> co-resident)
#define SBV    131072000    // S*B*V logits element count

typedef __bf16 bf16x8 __attribute__((ext_vector_type(8)));
typedef float  f32x4  __attribute__((ext_vector_type(4)));
typedef unsigned short u16;

__device__ __forceinline__ u16 f2bf(float f) {
  union { float f; unsigned u; } c; c.f = f;
  return (u16)((c.u + 0x7fffu + ((c.u >> 16) & 1u)) >> 16);  // RNE
}
__device__ __forceinline__ float sigm(float x) { return 1.f / (1.f + __expf(-x)); }
__device__ __forceinline__ float tanh_f(float x) { return 2.f / (1.f + __expf(-2.f * x)) - 1.f; }

// ---------------- prep kernels ----------------

__global__ void k_cvtv(const float* __restrict__ src, u16* __restrict__ dst, int n4) {
  const float4* s4 = (const float4*)src;
  ushort4* d4 = (ushort4*)dst;
  for (int i = blockIdx.x * blockDim.x + threadIdx.x; i < n4; i += gridDim.x * blockDim.x) {
    float4 v = s4[i];
    ushort4 o; o.x = f2bf(v.x); o.y = f2bf(v.y); o.z = f2bf(v.z); o.w = f2bf(v.w);
    d4[i] = o;
  }
}

__global__ void k_pack3(const float* __restrict__ sx, const float* __restrict__ sz,
                        const float* __restrict__ sh, int srcOff, u16* __restrict__ dst) {
  int i = blockIdx.x * blockDim.x + threadIdx.x;  // over 3M/4 float4s
  if (i >= 786432) return;
  int g = i >> 18;            // 0..2 gate
  int r4 = i & 262143;        // float4 index within 1M-elem matrix
  const float* s = (g == 0 ? sx : (g == 1 ? sz : sh)) + srcOff;
  float4 v = ((const float4*)s)[r4];
  ushort4 o; o.x = f2bf(v.x); o.y = f2bf(v.y); o.z = f2bf(v.z); o.w = f2bf(v.w);
  ((ushort4*)dst)[i] = o;
}

__global__ void k_embed(const int* __restrict__ idx, const float* __restrict__ emb,
                        u16* __restrict__ xe) {
  int i = blockIdx.x * blockDim.x + threadIdx.x;  // over 4096*256 float4s
  if (i >= 1048576) return;
  int row = i >> 8, k4 = i & 255;
  int e = idx[row];
  float4 v = ((const float4*)emb)[(size_t)e * 256 + k4];
  ushort4 o; o.x = f2bf(v.x); o.y = f2bf(v.y); o.z = f2bf(v.z); o.w = f2bf(v.w);
  ((ushort4*)xe)[i] = o;
}

// ---------------- GEMM: C[M,N] = A[M,K] @ B[N,K]^T (+bias), bf16 in / fp32 out ----------------
template<bool BIAS>
__global__ __launch_bounds__(256) void gemm_bt(const u16* __restrict__ A, const u16* __restrict__ Bm,
                                               float* __restrict__ C, const float* __restrict__ bias,
                                               int M, int N, int K, int mtiles) {
  __shared__ u16 As[128 * 32];
  __shared__ u16 Bs[128 * 32];
  const int tid = threadIdx.x;
  const int bm = blockIdx.x % mtiles, bn = blockIdx.x / mtiles;
  const int m0 = bm * 128, n0 = bn * 128;
  const int lane = tid & 63, w = tid >> 6, wm = w & 1, wn = w >> 1;
  const int la = lane & 15, lk = lane >> 4;
  const int srow = tid >> 2, sk = (tid & 3) * 8;
  f32x4 acc[4][4] = {};
  for (int kt = 0; kt < K; kt += 32) {
    const u16* srcA0 = A + (size_t)(m0 + srow) * K + kt + sk;
    const u16* srcA1 = A + (size_t)(m0 + srow + 64) * K + kt + sk;
    const u16* srcB0 = Bm + (size_t)(n0 + srow) * K + kt + sk;
    const u16* srcB1 = Bm + (size_t)(n0 + srow + 64) * K + kt + sk;
    __builtin_amdgcn_global_load_lds((const __attribute__((address_space(1))) void*)srcA0,
        (__attribute__((address_space(3))) void*)((char*)As + tid * 16), 16, 0, 0);
    __builtin_amdgcn_global_load_lds((const __attribute__((address_space(1))) void*)srcA1,
        (__attribute__((address_space(3))) void*)((char*)As + 4096 + tid * 16), 16, 0, 0);
    __builtin_amdgcn_global_load_lds((const __attribute__((address_space(1))) void*)srcB0,
        (__attribute__((address_space(3))) void*)((char*)Bs + tid * 16), 16, 0, 0);
    __builtin_amdgcn_global_load_lds((const __attribute__((address_space(1))) void*)srcB1,
        (__attribute__((address_space(3))) void*)((char*)Bs + 4096 + tid * 16), 16, 0, 0);
    __syncthreads();
    bf16x8 av[4], bv[4];
    #pragma unroll
    for (int m = 0; m < 4; ++m)
      av[m] = *(const bf16x8*)(As + (wm * 64 + m * 16 + la) * 32 + lk * 8);
    #pragma unroll
    for (int n = 0; n < 4; ++n)
      bv[n] = *(const bf16x8*)(Bs + (wn * 64 + n * 16 + la) * 32 + lk * 8);
    #pragma unroll
    for (int m = 0; m < 4; ++m)
      #pragma unroll
      for (int n = 0; n < 4; ++n)
        acc[m][n] = __builtin_amdgcn_mfma_f32_16x16x32_bf16(av[m], bv[n], acc[m][n], 0, 0, 0);
    __syncthreads();
  }
  #pragma unroll
  for (int n = 0; n < 4; ++n) {
    const int gc = n0 + wn * 64 + n * 16 + la;
    const float bb = BIAS ? bias[gc] : 0.f;
    #pragma unroll
    for (int m = 0; m < 4; ++m) {
      const int gr0 = m0 + wm * 64 + m * 16 + lk * 4;
      #pragma unroll
      for (int r = 0; r < 4; ++r)
        C[(size_t)(gr0 + r) * N + gc] = acc[m][n][r] + bb;
    }
  }
}

// ---------------- persistent recurrence ----------------
// 4 independent 32-block chains {layer,bg}: block (L,bg,cc) writes rows [bg*32,+32)
// and reads only rows of its own bg. All cross-block arrays are t-indexed/write-once
// -> no WAR hazards, arbitrary skew between chains is safe. L1 chases L0 via a
// one-directional flag check. Arrival = one sc1 dword store; wait = all waves poll
// their group's 32 flags directly (2 serialized LLC RTs/phase, no central release).
// Hang guards sized ~50ms/wait so a logic bug fails validation fast instead of
// wedging the container during graph replay.

__device__ __forceinline__ void waitg(const unsigned* f, unsigned tgt, int lane) {
  if (tgt == 0) return;
  unsigned g = 0;
  while (true) {
    bool ok = true;
    if (lane < 8) {
      uint4 v; const uint4* p = (const uint4*)f + lane;
      asm volatile("global_load_dwordx4 %0, %1, off sc1\ns_waitcnt vmcnt(0)"
                   : "=v"(v) : "v"(p) : "memory");
      ok = v.x >= tgt && v.y >= tgt && v.z >= tgt && v.w >= tgt;
    }
    if (__all(ok)) break;
    __builtin_amdgcn_s_sleep(1);
    if (++g > 2000000u) break;  // hang guard (~50ms)
  }
}

__device__ __forceinline__ void waitg2(const unsigned* f0, unsigned t0,
                                       const unsigned* f1, unsigned t1, int lane) {
  unsigned g = 0;
  while (true) {
    bool ok = true;
    if (lane < 16) {
      const unsigned* f = (lane < 8) ? f0 : f1;
      unsigned tgt = (lane < 8) ? t0 : t1;
      uint4 v; const uint4* p = (const uint4*)f + (lane & 7);
      asm volatile("global_load_dwordx4 %0, %1, off sc1\ns_waitcnt vmcnt(0)"
                   : "=v"(v) : "v"(p) : "memory");
      ok = v.x >= tgt && v.y >= tgt && v.z >= tgt && v.w >= tgt;
    }
    if (__all(ok)) break;
    __builtin_amdgcn_s_sleep(1);
    if (++g > 2000000u) break;
  }
}

__device__ __forceinline__ void arrive(unsigned* myFlag, unsigned val, int tid) {
  __syncthreads();                                   // all waves drained their stores
  if (tid == 0)
    asm volatile("global_store_dword %0, %1, off sc1" :: "v"(myFlag), "v"(val) : "memory");
}

// ---- full-tile staging (BIG): [32][1024] bf16 = 64KB, 4096 16B-chunks, 16/thread ----
__device__ __forceinline__ void stageF1(const u16* __restrict__ g, char* s, int tid) {
  uint4 t[16];
  #pragma unroll
  for (int i = 0; i < 16; ++i) {
    int c = i * 256 + tid;                    // 0..4095
    const u16* p = g + (c >> 7) * 1024 + (c & 127) * 8;
    asm volatile("global_load_dwordx4 %0, %1, off sc1" : "=v"(t[i]) : "v"(p));
  }
  asm volatile("s_waitcnt vmcnt(0)" ::: "memory");
  #pragma unroll
  for (int i = 0; i < 16; ++i) {
    int c = i * 256 + tid;
    int row = c >> 7, cb = (c & 127) * 16;
    *(uint4*)(s + ((row * 2048 + cb) ^ ((row & 7) << 4))) = t[i];
  }
}
__device__ __forceinline__ void stageF2(const u16* __restrict__ gA, const u16* __restrict__ gB,
                                        char* sA, char* sB, int tid) {
  uint4 ta[16], tb[16];
  #pragma unroll
  for (int i = 0; i < 16; ++i) {
    int c = i * 256 + tid;
    const u16* pa = gA + (c >> 7) * 1024 + (c & 127) * 8;
    const u16* pb = gB + (c >> 7) * 1024 + (c & 127) * 8;
    asm volatile("global_load_dwordx4 %0, %1, off sc1" : "=v"(ta[i]) : "v"(pa));
    asm volatile("global_load_dwordx4 %0, %1, off sc1" : "=v"(tb[i]) : "v"(pb));
  }
  asm volatile("s_waitcnt vmcnt(0)" ::: "memory");
  #pragma unroll
  for (int i = 0; i < 16; ++i) {
    int c = i * 256 + tid;
    int row = c >> 7, cb = (c & 127) * 16;
    int off = (row * 2048 + cb) ^ ((row & 7) << 4);
    *(uint4*)(sA + off) = ta[i];
    *(uint4*)(sB + off) = tb[i];
  }
}
__device__ __forceinline__ bf16x8 ldsF(const char* s, int row, int ks, int lk) {
  return *(const bf16x8*)(s + ((row * 2048 + ks * 64 + lk * 16) ^ ((row & 7) << 4)));
}

// ---- half-tile staging (fallback, 64KB LDS) ----
__device__ __forceinline__ void stageH1(const u16* __restrict__ g, int half, char* s, int tid) {
  uint4 t[8];
  #pragma unroll
  for (int i = 0; i < 8; ++i) {
    int c = i * 256 + tid;                    // 0..2047
    const u16* p = g + (c >> 6) * 1024 + half * 512 + (c & 63) * 8;
    asm volatile("global_load_dwordx4 %0, %1, off sc1" : "=v"(t[i]) : "v"(p));
  }
  asm volatile("s_waitcnt vmcnt(0)" ::: "memory");
  #pragma unroll
  for (int i = 0; i < 8; ++i) {
    int c = i * 256 + tid;
    int row = c >> 6, cb = (c & 63) * 16;
    *(uint4*)(s + ((row * 1024 + cb) ^ ((row & 7) << 4))) = t[i];
  }
}
__device__ __forceinline__ void stageH2(const u16* __restrict__ gA, const u16* __restrict__ gB,
                                        int half, char* sA, char* sB, int tid) {
  uint4 ta[8], tb[8];
  #pragma unroll
  for (int i = 0; i < 8; ++i) {
    int c = i * 256 + tid;
    int row = c >> 6, ce = (c & 63) * 8;
    const u16* pa = gA + row * 1024 + half * 512 + ce;
    const u16* pb = gB + row * 1024 + half * 512 + ce;
    asm volatile("global_load_dwordx4 %0, %1, off sc1" : "=v"(ta[i]) : "v"(pa));
    asm volatile("global_load_dwordx4 %0, %1, off sc1" : "=v"(tb[i]) : "v"(pb));
  }
  asm volatile("s_waitcnt vmcnt(0)" ::: "memory");
  #pragma unroll
  for (int i = 0; i < 8; ++i) {
    int c = i * 256 + tid;
    int row = c >> 6, cb = (c & 63) * 16;
    int off = (row * 1024 + cb) ^ ((row & 7) << 4);
    *(uint4*)(sA + off) = ta[i];
    *(uint4*)(sB + off) = tb[i];
  }
}
__device__ __forceinline__ bf16x8 ldsH(const char* s, int row, int ksl, int lk) {
  return *(const bf16x8*)(s + ((row * 1024 + ksl * 64 + lk * 16) ^ ((row & 7) << 4)));
}

template<bool BIG>
__global__ __launch_bounds__(256) void k_recur(
    const u16* __restrict__ hinitb,    // [2][64][1024] bf16 of initial hidden
    const float* __restrict__ hidden,  // [2][64][1024] fp32
    const float* __restrict__ X0,      // [64][64][3072] layer-0 x-projections
    const u16* __restrict__ Ucat0, const u16* __restrict__ Ucat1,  // [3072][1024] {Ur|Uz|Uh}
    const u16* __restrict__ Wcat1,                                  // [3072][1024] {Wx|Wz|Wh} layer1
    const float* __restrict__ br, const float* __restrict__ bz, const float* __restrict__ bh,
    u16* __restrict__ H0seq, u16* __restrict__ H1seq,  // [64][64][1024] bf16 hidden per step
    u16* __restrict__ RH0, u16* __restrict__ RH1,      // [64][64][1024] bf16 r*h per step
    float* __restrict__ houtf,                          // d_out + SBV : [2][64][1024]
    unsigned* flags) {
  extern __shared__ char sMem[];
  char* sA = sMem;
  char* sX = sMem + (BIG ? 65536 : 32768);
  const int tid = threadIdx.x, bid = blockIdx.x;
  const int layer = bid >> 6, r6 = bid & 63, bg = r6 >> 5, cc = r6 & 31;
  const int lane = tid & 63, w = tid >> 6, wm = w & 1, wn = w >> 1;
  const int la = lane & 15, lk = lane >> 4;
  const int rowbase = bg * 32;
  const int b0 = rowbase + wm * 16;   // wave's first batch row (global)
  const int rowA = wm * 16 + la;      // A-operand row, local to staged tile
  const int j0 = cc * 32 + wn * 16;   // wave's first output col
  const int jl = j0 + la;             // this lane's output col (C/D: col = lane&15)
  const u16* Ucat = layer ? Ucat1 : Ucat0;
  u16* Hseq = layer ? H1seq : H0seq;
  u16* RHl = layer ? RH1 : RH0;
  const u16* hinit = hinitb + layer * 65536;
  unsigned* fSelf = flags + (layer * 2 + bg) * 32;   // this chain's 32 flags
  unsigned* fX    = flags + bg * 32;                 // L0 chain of same bg (for L1)
  unsigned* myFlag = fSelf + cc;

  float h_reg[4], z_reg[4];
  #pragma unroll
  for (int r = 0; r < 4; ++r)
    h_reg[r] = hidden[layer * 65536 + (b0 + lk * 4 + r) * 1024 + jl];
  const float bR = br[layer * 1024 + jl], bZ = bz[layer * 1024 + jl], bH = bh[layer * 1024 + jl];

  // per-lane weight row bases (B-operand: col = lane&15, k-chunk = lane>>4); cached loads
  const u16* BrR = Ucat + ((size_t)(j0 + la)) * 1024 + lk * 8;
  const u16* BrZ = Ucat + ((size_t)(1024 + j0 + la)) * 1024 + lk * 8;
  const u16* BrH = Ucat + ((size_t)(2048 + j0 + la)) * 1024 + lk * 8;
  const u16* WrR = Wcat1 + ((size_t)(j0 + la)) * 1024 + lk * 8;
  const u16* WrZ = Wcat1 + ((size_t)(1024 + j0 + la)) * 1024 + lk * 8;
  const u16* WrH = Wcat1 + ((size_t)(2048 + j0 + la)) * 1024 + lk * 8;

  for (int t = 0; t < 64; ++t) {
    // ================= phase A: r,z gates =================
    const u16* hsrc = ((t == 0) ? hinit : (Hseq + (size_t)(t - 1) * 65536)) + rowbase * 1024;
    const u16* xsrc = H0seq + (size_t)t * 65536 + rowbase * 1024;
    f32x4 accR = {0.f, 0.f, 0.f, 0.f}, accZ = {0.f, 0.f, 0.f, 0.f};
    if (layer == 0) {
      waitg(fSelf, 2 * t, lane);           // own chain's B of t-1
      if (BIG) {
        stageF1(hsrc, sA, tid);
        __syncthreads();
        #pragma unroll 8
        for (int ks = 0; ks < 32; ++ks) {
          bf16x8 a = ldsF(sA, rowA, ks, lk);
          accR = __builtin_amdgcn_mfma_f32_16x16x32_bf16(a, *(const bf16x8*)(BrR + ks * 32), accR, 0, 0, 0);
          accZ = __builtin_amdgcn_mfma_f32_16x16x32_bf16(a, *(const bf16x8*)(BrZ + ks * 32), accZ, 0, 0, 0);
        }
      } else {
        for (int half = 0; half < 2; ++half) {
          stageH1(hsrc, half, sA, tid);
          __syncthreads();
          #pragma unroll 4
          for (int ksl = 0; ksl < 16; ++ksl) {
            const int ks = half * 16 + ksl;
            bf16x8 a = ldsH(sA, rowA, ksl, lk);
            accR = __builtin_amdgcn_mfma_f32_16x16x32_bf16(a, *(const bf16x8*)(BrR + ks * 32), accR, 0, 0, 0);
            accZ = __builtin_amdgcn_mfma_f32_16x16x32_bf16(a, *(const bf16x8*)(BrZ + ks * 32), accZ, 0, 0, 0);
          }
          __syncthreads();
        }
      }
    } else {
      waitg2(fSelf, 2 * t, fX, 2 * t + 2, lane);   // own B(t-1) AND L0's B(t)
      if (BIG) {
        stageF2(hsrc, xsrc, sA, sX, tid);
        __syncthreads();
        #pragma unroll 4
        for (int ks = 0; ks < 32; ++ks) {
          bf16x8 a = ldsF(sA, rowA, ks, lk);
          bf16x8 x = ldsF(sX, rowA, ks, lk);
          accR = __builtin_amdgcn_mfma_f32_16x16x32_bf16(a, *(const bf16x8*)(BrR + ks * 32), accR, 0, 0, 0);
          accZ = __builtin_amdgcn_mfma_f32_16x16x32_bf16(a, *(const bf16x8*)(BrZ + ks * 32), accZ, 0, 0, 0);
          accR = __builtin_amdgcn_mfma_f32_16x16x32_bf16(x, *(const bf16x8*)(WrR + ks * 32), accR, 0, 0, 0);
          accZ = __builtin_amdgcn_mfma_f32_16x16x32_bf16(x, *(const bf16x8*)(WrZ + ks * 32), accZ, 0, 0, 0);
        }
      } else {
        for (int half = 0; half < 2; ++half) {
          stageH2(hsrc, xsrc, half, sA, sX, tid);
          __syncthreads();
          #pragma unroll 4
          for (int ksl = 0; ksl < 16; ++ksl) {
            const int ks = half * 16 + ksl;
            bf16x8 a = ldsH(sA, rowA, ksl, lk);
            bf16x8 x = ldsH(sX, rowA, ksl, lk);
            accR = __builtin_amdgcn_mfma_f32_16x16x32_bf16(a, *(const bf16x8*)(BrR + ks * 32), accR, 0, 0, 0);
            accZ = __builtin_amdgcn_mfma_f32_16x16x32_bf16(a, *(const bf16x8*)(BrZ + ks * 32), accZ, 0, 0, 0);
            accR = __builtin_amdgcn_mfma_f32_16x16x32_bf16(x, *(const bf16x8*)(WrR + ks * 32), accR, 0, 0, 0);
            accZ = __builtin_amdgcn_mfma_f32_16x16x32_bf16(x, *(const bf16x8*)(WrZ + ks * 32), accZ, 0, 0, 0);
          }
          __syncthreads();
        }
      }
    }
    #pragma unroll
    for (int r = 0; r < 4; ++r) {
      const int row = b0 + lk * 4 + r;  // C/D: row = (lane>>4)*4 + reg
      float pr = accR[r] + bR, pz = accZ[r] + bZ;
      if (layer == 0) {
        const float* xp = X0 + ((size_t)(t * 64 + row)) * 3072 + jl;
        pr += xp[0]; pz += xp[1024];
      }
      float rv = sigm(pr);
      z_reg[r] = sigm(pz);
      unsigned v = f2bf(rv * h_reg[r]);
      u16* p = RHl + (size_t)(t * 64 + row) * 1024 + jl;
      asm volatile("global_store_short %0, %1, off sc1" :: "v"(p), "v"(v));
    }
    asm volatile("s_waitcnt vmcnt(0)" ::: "memory");
    arrive(myFlag, 2 * t + 1, tid);
    // ================= phase B: candidate + state update =================
    const u16* rhsrc = RHl + (size_t)t * 65536 + rowbase * 1024;
    f32x4 accH = {0.f, 0.f, 0.f, 0.f};
    waitg(fSelf, 2 * t + 1, lane);
    if (BIG) {
      stageF1(rhsrc, sA, tid);          // sX still holds x (layer 1)
      __syncthreads();
      if (layer == 0) {
        #pragma unroll 8
        for (int ks = 0; ks < 32; ++ks) {
          bf16x8 a = ldsF(sA, rowA, ks, lk);
          accH = __builtin_amdgcn_mfma_f32_16x16x32_bf16(a, *(const bf16x8*)(BrH + ks * 32), accH, 0, 0, 0);
        }
      } else {
        #pragma unroll 8
        for (int ks = 0; ks < 32; ++ks) {
          bf16x8 a = ldsF(sA, rowA, ks, lk);
          bf16x8 x = ldsF(sX, rowA, ks, lk);
          accH = __builtin_amdgcn_mfma_f32_16x16x32_bf16(a, *(const bf16x8*)(BrH + ks * 32), accH, 0, 0, 0);
          accH = __builtin_amdgcn_mfma_f32_16x16x32_bf16(x, *(const bf16x8*)(WrH + ks * 32), accH, 0, 0, 0);
        }
      }
    } else {
      const u16* xsrc2 = H0seq + (size_t)t * 65536 + rowbase * 1024;
      for (int half = 0; half < 2; ++half) {
        if (layer == 0) {
          stageH1(rhsrc, half, sA, tid);
          __syncthreads();
          #pragma unroll 4
          for (int ksl = 0; ksl < 16; ++ksl) {
            const int ks = half * 16 + ksl;
            bf16x8 a = ldsH(sA, rowA, ksl, lk);
            accH = __builtin_amdgcn_mfma_f32_16x16x32_bf16(a, *(const bf16x8*)(BrH + ks * 32), accH, 0, 0, 0);
          }
        } else {
          stageH2(rhsrc, xsrc2, half, sA, sX, tid);
          __syncthreads();
          #pragma unroll 4
          for (int ksl = 0; ksl < 16; ++ksl) {
            const int ks = half * 16 + ksl;
            bf16x8 a = ldsH(sA, rowA, ksl, lk);
            bf16x8 x = ldsH(sX, rowA, ksl, lk);
            accH = __builtin_amdgcn_mfma_f32_16x16x32_bf16(a, *(const bf16x8*)(BrH + ks * 32), accH, 0, 0, 0);
            accH = __builtin_amdgcn_mfma_f32_16x16x32_bf16(x, *(const bf16x8*)(WrH + ks * 32), accH, 0, 0, 0);
          }
        }
        __syncthreads();
      }
    }
    #pragma unroll
    for (int r = 0; r < 4; ++r) {
      const int row = b0 + lk * 4 + r;
      float pre = accH[r] + bH;
      if (layer == 0) pre += X0[((size_t)(t * 64 + row)) * 3072 + 2048 + jl];
      float hc = tanh_f(pre);
      float hn = h_reg[r] + z_reg[r] * (hc - h_reg[r]);  // (1-z)h + z*hcand
      h_reg[r] = hn;
      unsigned v = f2bf(hn);
      u16* p = Hseq + (size_t)(t * 64 + row) * 1024 + jl;
      asm volatile("global_store_short %0, %1, off sc1" :: "v"(p), "v"(v));
      if (t == 63) houtf[layer * 65536 + row * 1024 + jl] = hn;
    }
    asm volatile("s_waitcnt vmcnt(0)" ::: "memory");
    arrive(myFlag, 2 * t + 2, tid);
  }
}

// ---------------- host launch ----------------
extern "C" void kernel_launch(void* const* d_in, const int* in_sizes, int n_in,
                              void* d_out, int out_size, void* d_ws, size_t ws_size,
                              hipStream_t stream) {
  const int* inputs = (const int*)d_in[0];
  const float* hidden = (const float*)d_in[1];
  const float* emb = (const float*)d_in[2];
  const float* Wx = (const float*)d_in[3];
  const float* Ur = (const float*)d_in[4];
  const float* br = (const float*)d_in[5];
  const float* Wz = (const float*)d_in[6];
  const float* Uz = (const float*)d_in[7];
  const float* bz = (const float*)d_in[8];
  const float* Wh = (const float*)d_in[9];
  const float* Uh = (const float*)d_in[10];
  const float* bh = (const float*)d_in[11];
  const float* decW = (const float*)d_in[12];
  const float* decb = (const float*)d_in[13];
  float* out = (float*)d_out;

  char* ws = (char*)d_ws;
  size_t off = 0;
  auto alloc = [&](size_t bytes) { char* p = ws + off; off += (bytes + 255) & ~(size_t)255; return p; };
  unsigned* flags = (unsigned*)alloc(4096);   // 4 chains x 32 flags
  u16* hinitb = (u16*)alloc((size_t)2 * 64 * 1024 * 2);
  u16* xe     = (u16*)alloc((size_t)4096 * 1024 * 2);
  u16* Wcat0b = (u16*)alloc((size_t)3072 * 1024 * 2);
  u16* Wcat1b = (u16*)alloc((size_t)3072 * 1024 * 2);
  u16* Ucat0b = (u16*)alloc((size_t)3072 * 1024 * 2);
  u16* Ucat1b = (u16*)alloc((size_t)3072 * 1024 * 2);
  u16* decWb  = (u16*)alloc((size_t)32000 * 1024 * 2);
  float* X0   = (float*)alloc((size_t)4096 * 3072 * 4);
  u16* H0seq  = (u16*)alloc((size_t)4096 * 1024 * 2);
  u16* H1seq  = (u16*)alloc((size_t)4096 * 1024 * 2);
  u16* RH0    = (u16*)alloc((size_t)4096 * 1024 * 2);
  u16* RH1    = (u16*)alloc((size_t)4096 * 1024 * 2);

  hipMemsetAsync(flags, 0, 4096, stream);
  k_cvtv<<<128, 256, 0, stream>>>(hidden, hinitb, 32768);
  k_pack3<<<3072, 256, 0, stream>>>(Wx, Wz, Wh, 0, Wcat0b);
  k_pack3<<<3072, 256, 0, stream>>>(Wx, Wz, Wh, 1048576, Wcat1b);
  k_pack3<<<3072, 256, 0, stream>>>(Ur, Uz, Uh, 0, Ucat0b);
  k_pack3<<<3072, 256, 0, stream>>>(Ur, Uz, Uh, 1048576, Ucat1b);
  k_embed<<<4096, 256, 0, stream>>>(inputs, emb, xe);
  k_cvtv<<<4096, 256, 0, stream>>>(decW, decWb, 8192000);

  // layer-0 x-projections for all timesteps: [4096,1024] @ [3072,1024]^T
  gemm_bt<false><<<768, 256, 0, stream>>>(xe, Wcat0b, X0, nullptr, 4096, 3072, 1024, 32);

  // pipelined 2-layer recurrence: 4 independent 32-block chains
  hipError_t eattr = hipFuncSetAttribute(reinterpret_cast<const void*>(&k_recur<true>),
                                         hipFuncAttributeMaxDynamicSharedMemorySize, 131072);
  if (eattr == hipSuccess) {
    k_recur<true><<<NB_REC, 256, 131072, stream>>>(hinitb, hidden, X0, Ucat0b, Ucat1b, Wcat1b,
                                                   br, bz, bh, H0seq, H1seq, RH0, RH1,
                                                   out + (size_t)SBV, flags);
  } else {
    (void)hipFuncSetAttribute(reinterpret_cast<const void*>(&k_recur<false>),
                              hipFuncAttributeMaxDynamicSharedMemorySize, 65536);
    k_recur<false><<<NB_REC, 256, 65536, stream>>>(hinitb, hidden, X0, Ucat0b, Ucat1b, Wcat1b,
                                                   br, bz, bh, H0seq, H1seq, RH0, RH1,
                                                   out + (size_t)SBV, flags);
  }

  // decoder: logits[4096,32000] = H1seq @ decW^T + bias
  gemm_bt<true><<<8000, 256, 0, stream>>>(H1seq, decWb, out, decb, 4096, 32000, 1024, 32);
}